// Round 6
// baseline (99.783 us; speedup 1.0000x reference)
//
#include <hip/hip_runtime.h>
#include <hip/hip_bf16.h>

// B=8, C=64, O=64, H=W=128, stride=1, pad=1, 3x3.
constexpr int Bc = 8;
constexpr int Cc = 64;
constexpr int Oc = 64;
constexpr int Hc = 128;
constexpr int Wc = 128;
constexpr int HWc = Hc * Wc;
constexpr int CP = 72;   // padded LDS row stride bf16 (144 B = 16B-aligned)

typedef __attribute__((ext_vector_type(8))) short short8;   // 8 x bf16
typedef __attribute__((ext_vector_type(4))) float floatx4;
typedef __attribute__((ext_vector_type(2))) float floatx2;

__device__ __forceinline__ float bperm(int idx4, float v) {
    return __int_as_float(__builtin_amdgcn_ds_bpermute(idx4, __float_as_int(v)));
}
// packed f32x2 -> bf16x2 (RNE), lo -> bits[15:0]
__device__ __forceinline__ unsigned cvt_pk_bf16(float lo, float hi) {
    unsigned r;
    asm("v_cvt_pk_bf16_f32 %0, %1, %2" : "=v"(r) : "v"(lo), "v"(hi));
    return r;
}

// v7: 4 independent convoys per CU (v6 post-mortem: kernel ~22us vs ~8us
// overlap floor; waste is BETWEEN the 2 resident barrier-domains marching in
// lockstep). One output ROW per block, 256 threads = 4 waves; grid 1024 ->
// 4 blocks/CU resident (LDS 21KB, VGPR<=128 -> 16 waves/CU in 4 domains).
// Wave = 16 channels; lane = pixel pair (2l,2l+1) float2 + bperm horizontal
// taps (v6's measured-cheap load pattern, 3 rows). A-frags from global core
// (L2-hot). s_setprio(1) around GEMM: role-diverse waves now share each CU.
// XCD remap kept: blk&7 = XCD, h ascending per XCD -> L2 row reuse.
__global__ __launch_bounds__(256, 4) void spconv_kernel(
    const float* __restrict__ x, const float* __restrict__ core,
    const float* __restrict__ peri, const float* __restrict__ thr,
    const float* __restrict__ scl, float* __restrict__ out)
{
    __shared__ __hip_bfloat16 s_selT[Wc][CP];   // [physw][c] 18432 B
    __shared__ float s_divp[4][Wc];             //             2048 B
    __shared__ float s_msk[Wc];                 // rare path    512 B

    const int tid = threadIdx.x;
    const int l   = tid & 63;                   // lane
    const int wv  = tid >> 6;                   // wave 0..3
    const int b   = blockIdx.x & 7;             // one image per XCD
    const int h   = blockIdx.x >> 3;            // row 0..127

    // GEMM geometry: wave wv owns o-quarter wv, all 8 w-tiles
    const int o0   = wv * 16;
    const int n    = l & 15;
    const int quad = l >> 4;

    // ---- A-fragments first (global core, L2-hot; consumed in Phase 3) ----
    const float* arow = core + (size_t)(o0 + n) * Cc + quad * 8;
    const floatx4 af0 = *(const floatx4*)(arow);        // k 0..3
    const floatx4 af1 = *(const floatx4*)(arow + 4);    // k 4..7
    const floatx4 af2 = *(const floatx4*)(arow + 32);   // k 32..35
    const floatx4 af3 = *(const floatx4*)(arow + 36);   // k 36..39
    union { unsigned u[4]; short8 s; } A0, A1;
    A0.u[0] = cvt_pk_bf16(af0.x, af0.y); A0.u[1] = cvt_pk_bf16(af0.z, af0.w);
    A0.u[2] = cvt_pk_bf16(af1.x, af1.y); A0.u[3] = cvt_pk_bf16(af1.z, af1.w);
    A1.u[0] = cvt_pk_bf16(af2.x, af2.y); A1.u[1] = cvt_pk_bf16(af2.z, af2.w);
    A1.u[2] = cvt_pk_bf16(af3.x, af3.y); A1.u[3] = cvt_pk_bf16(af3.z, af3.w);

    // ---- Phase 1: taps. Lane owns px 2l,2l+1; wave owns 16 channels ----
    const int upIdx = ((l - 1) & 63) << 2;      // bperm byte idx: lane l-1
    const int dnIdx = ((l + 1) & 63) << 2;      // lane l+1
    const float lzf = (l == 0)  ? 0.f : 1.f;    // w=0 left pad
    const float rzf = (l == 63) ? 0.f : 1.f;    // w=127 right pad
    const float mUf = (h > 0) ? 1.f : 0.f;
    const float mDf = (h < Hc - 1) ? 1.f : 0.f;
    const int   dU  = (h > 0) ? -Wc : 0;        // clamped row offsets
    const int   dD  = (h < Hc - 1) ? Wc : 0;

    const float p0 = peri[0], p1 = peri[1], p2 = peri[2], p3 = peri[3];
    const float p4 = peri[4], p5 = peri[5], p6 = peri[6], p7 = peri[7];
    const float thrv = thr[0], sclv = scl[0];

    const float* xw = x + (size_t)b * Cc * HWc + (size_t)h * Wc + 2 * l;
    const float* xb = x + (size_t)b * Cc * HWc + (size_t)h * Wc;

    float dlo = 0.f, dhi = 0.f;

// One channel: RM/R0/R1 = rows h-1,h,h+1 (vert pre-masked), K = slot in pair.
#define PROC1(RM, R0, R1, K) do {                                             \
    const float rmL = lzf * bperm(upIdx, RM.y);                               \
    const float r0L = lzf * bperm(upIdx, R0.y);                               \
    const float r1L = lzf * bperm(upIdx, R1.y);                               \
    const float rmR = rzf * bperm(dnIdx, RM.x);                               \
    const float r0R = rzf * bperm(dnIdx, R0.x);                               \
    const float r1R = rzf * bperm(dnIdx, R1.x);                               \
    { const float t = R0.x;  /* pixel lo (w=2l) */                            \
      float a = p0 * rmL; a = fmaf(p1, RM.x, a); a = fmaf(p2, RM.y, a);       \
      a = fmaf(p3, r0L, a); a = fmaf(p4, R0.y, a);                            \
      a = fmaf(p5, r1L, a); a = fmaf(p6, R1.x, a); a = fmaf(p7, R1.y, a);     \
      aLo[K] = a; float e;                                                    \
      e = rmL  - t; dlo = fmaf(e, e, dlo); e = RM.x - t; dlo = fmaf(e, e, dlo); \
      e = RM.y - t; dlo = fmaf(e, e, dlo); e = r0L  - t; dlo = fmaf(e, e, dlo); \
      e = R0.y - t; dlo = fmaf(e, e, dlo); e = r1L  - t; dlo = fmaf(e, e, dlo); \
      e = R1.x - t; dlo = fmaf(e, e, dlo); e = R1.y - t; dlo = fmaf(e, e, dlo); } \
    { const float t = R0.y;  /* pixel hi (w=2l+1) */                          \
      float a = p0 * RM.x; a = fmaf(p1, RM.y, a); a = fmaf(p2, rmR, a);       \
      a = fmaf(p3, R0.x, a); a = fmaf(p4, r0R, a);                            \
      a = fmaf(p5, R1.x, a); a = fmaf(p6, R1.y, a); a = fmaf(p7, r1R, a);     \
      aHi[K] = a; float e;                                                    \
      e = RM.x - t; dhi = fmaf(e, e, dhi); e = RM.y - t; dhi = fmaf(e, e, dhi); \
      e = rmR  - t; dhi = fmaf(e, e, dhi); e = R0.x - t; dhi = fmaf(e, e, dhi); \
      e = r0R  - t; dhi = fmaf(e, e, dhi); e = R1.x - t; dhi = fmaf(e, e, dhi); \
      e = R1.y - t; dhi = fmaf(e, e, dhi); e = r1R  - t; dhi = fmaf(e, e, dhi); } \
} while (0)

    #pragma unroll 2
    for (int j = 0; j < 8; ++j) {               // 8 channel pairs = 16 ch
        const int c0 = wv * 16 + 2 * j;
        const float* b0p = xw + (size_t)c0 * HWc;
        const float* b1p = b0p + HWc;

        floatx2 rm0 = *(const floatx2*)(b0p + dU);
        floatx2 r00 = *(const floatx2*)(b0p);
        floatx2 r10 = *(const floatx2*)(b0p + dD);
        floatx2 rm1 = *(const floatx2*)(b1p + dU);
        floatx2 r01 = *(const floatx2*)(b1p);
        floatx2 r11 = *(const floatx2*)(b1p + dD);
        rm0 *= mUf; r10 *= mDf; rm1 *= mUf; r11 *= mDf;   // zero padded rows

        float aLo[2], aHi[2];
        PROC1(rm0, r00, r10, 0);
        PROC1(rm1, r01, r11, 1);

        // packed bf16x2 writes; phys rows: w=2l -> l, w=2l+1 -> 64+l
        *(unsigned*)&s_selT[l]      [c0] = cvt_pk_bf16(aLo[0], aLo[1]);
        *(unsigned*)&s_selT[64 + l] [c0] = cvt_pk_bf16(aHi[0], aHi[1]);
    }
#undef PROC1

    {   // div partials (logical w indexing), one slot per wave
        floatx2 dv = {dlo, dhi};
        *(floatx2*)&s_divp[wv][2 * l] = dv;
    }
    __syncthreads();        // the ONLY barrier in the common path

    // ---- mask check: each lane reduces its own 2 pixels (4 b64 reads) ----
    floatx2 sum2 = {0.f, 0.f};
    #pragma unroll
    for (int g = 0; g < 4; ++g)
        sum2 += *(const floatx2*)&s_divp[g][2 * l];
    const bool badLo = ((sum2.x - thrv) * sclv) <= 0.f;   // !(sigmoid>0.5)
    const bool badHi = ((sum2.y - thrv) * sclv) <= 0.f;
    if (__any(badLo || badHi)) {
        // ---- rare path: fully barriered fixup ----
        if (wv == 0) {
            s_msk[2 * l]     = badLo ? 0.f : 1.f;
            s_msk[2 * l + 1] = badHi ? 0.f : 1.f;
        }
        __syncthreads();
        #pragma unroll
        for (int i = 0; i < 32; ++i) {          // 8192 elems / 256 thr
            const int idx = i * 256 + tid;
            const int p   = idx & (Wc - 1);                // phys row
            const int c   = idx >> 7;
            const int ww  = ((p & 63) << 1) | (p >> 6);    // logical w
            if (s_msk[ww] == 0.f)
                s_selT[p][c] = __float2bfloat16(xb[(size_t)c * HWc + ww]);
        }
        __syncthreads();
    }

    // ---- Phase 3: MFMA GEMM: D[o][w] = core[o][c] * sel[c][w], K=64 ----
    float* outb = out + ((size_t)(b * Oc) * Hc + h) * Wc;

    __builtin_amdgcn_s_setprio(1);
    #pragma unroll
    for (int t = 0; t < 8; ++t) {               // 8 w-tiles per wave
        const int w0   = t * 16;
        const int wlog = w0 + n;
        const int pr   = ((wlog >> 1) & 63) | ((wlog & 1) << 6);
        const short8 b0 = *(const short8*)&s_selT[pr][quad * 8];
        const short8 b1 = *(const short8*)&s_selT[pr][quad * 8 + 32];
        floatx4 acc = {0.f, 0.f, 0.f, 0.f};
        acc = __builtin_amdgcn_mfma_f32_16x16x32_bf16(A0.s, b0, acc, 0, 0, 0);
        acc = __builtin_amdgcn_mfma_f32_16x16x32_bf16(A1.s, b1, acc, 0, 0, 0);
        #pragma unroll
        for (int r = 0; r < 4; ++r) {
            const int o = o0 + quad * 4 + r;
            outb[(size_t)o * HWc + w0 + n] = acc[r];
        }
    }
    __builtin_amdgcn_s_setprio(0);
}

extern "C" void kernel_launch(void* const* d_in, const int* in_sizes, int n_in,
                              void* d_out, int out_size, void* d_ws, size_t ws_size,
                              hipStream_t stream) {
    const float* x    = (const float*)d_in[0];
    const float* core = (const float*)d_in[1];
    const float* peri = (const float*)d_in[2];
    const float* thr  = (const float*)d_in[3];
    const float* scl  = (const float*)d_in[4];
    float* out = (float*)d_out;

    spconv_kernel<<<dim3(Bc * Hc), dim3(256), 0, stream>>>(
        x, core, peri, thr, scl, out);
}